// Round 1
// baseline (7828.963 us; speedup 1.0000x reference)
//
#include <hip/hip_runtime.h>

// ---------------- problem constants ----------------
#define B_ 32
#define S_ 64
#define C_ 512
#define E_ 256
#define H_ 512
#define V_ 32000
#define T_ 32
#define NBLK 256       // grid blocks (persistent kernel)
#define NTHR 256
#define NVB 250        // blocks active in logits phase (250*128 = 32000)
#define VT 128         // vocab tile per block
#define START_TOK 1

// ---------------- workspace layout (float offsets) ----------------
#define OFF_BAR  0          // 2 uints: barrier count, generation
#define OFF_CS   64         // cscore[32][64]  (context part of attn score + ba)
#define OFF_LSE  2112       // lse_prev[32]
#define OFF_APV  2176       // argmax partial value [32][256]
#define OFF_API  10368      // argmax partial index [32][256] (int)
#define OFF_LSM  18560      // lse partial max [32][256]
#define OFF_LSS  26752      // lse partial sum [32][256]
#define OFF_INPT 34944      // inpT[768][32]   ([ex | attend] transposed)
#define OFF_H0   59520      // h0T[2][512][32] ping-pong
#define OFF_H1   92288      // h1T[2][512][32] ping-pong
#define OFF_W0I  125056     // WihT0 [768][1536]
#define OFF_W0H  1304704    // WhhT0 [512][1536]
#define OFF_W1I  2091136    // WihT1 [512][1536]
#define OFF_W1H  2877568    // WhhT1 [512][1536]
#define OFF_WOT  3664000    // WoT   [512][32000]
#define WS_FLOATS 20048000  // ~80.2 MB

struct Params {
  const float* ctx; const float* embed; const float* Wa;
  const float* bih0; const float* bhh0; const float* bih1; const float* bhh1;
  const float* bo;
  float* ws; float* out;
};

__device__ __forceinline__ float sigf(float x) { return 1.0f / (1.0f + expf(-x)); }

// -------- device-scope grid barrier (all NBLK blocks co-resident) --------
__device__ __forceinline__ void gbar(unsigned* bar) {
  __syncthreads();
  if (threadIdx.x == 0) {
    __builtin_amdgcn_fence(__ATOMIC_RELEASE, "agent");
    unsigned g = __hip_atomic_load(bar + 1, __ATOMIC_RELAXED, __HIP_MEMORY_SCOPE_AGENT);
    unsigned a = __hip_atomic_fetch_add(bar, 1u, __ATOMIC_RELAXED, __HIP_MEMORY_SCOPE_AGENT);
    if (a == NBLK - 1) {
      __hip_atomic_store(bar, 0u, __ATOMIC_RELAXED, __HIP_MEMORY_SCOPE_AGENT);
      __hip_atomic_store(bar + 1, g + 1u, __ATOMIC_RELEASE, __HIP_MEMORY_SCOPE_AGENT);
    } else {
      while (__hip_atomic_load(bar + 1, __ATOMIC_RELAXED, __HIP_MEMORY_SCOPE_AGENT) == g) {
        __builtin_amdgcn_s_sleep(2);
      }
    }
    __builtin_amdgcn_fence(__ATOMIC_ACQUIRE, "agent");
  }
  __syncthreads();
}

// ---------------- prologue kernels ----------------
__global__ void __launch_bounds__(256) zero_k(float* wsf) {
  const unsigned i = blockIdx.x * 256u + threadIdx.x;
  if (i < 2u) ((unsigned*)wsf)[OFF_BAR + i] = 0u;
  if (i < 65536u) wsf[OFF_H0 + i] = 0.0f;   // h0T[2] + h1T[2] contiguous
}

__global__ void __launch_bounds__(256) cscore_k(const float* __restrict__ ctx,
                                                const float* __restrict__ Wa,
                                                const float* __restrict__ ba,
                                                float* __restrict__ wsf) {
  const int b = blockIdx.x;
  const int s = threadIdx.x >> 2, q = threadIdx.x & 3;
  const float* cp = ctx + ((size_t)b * S_ + s) * C_ + q * 128;
  const float* wp = Wa + H_ + q * 128;     // context half of Wa
  float acc = 0.f;
#pragma unroll 8
  for (int k = 0; k < 128; ++k) acc = fmaf(cp[k], wp[k], acc);
  acc += __shfl_xor(acc, 1);
  acc += __shfl_xor(acc, 2);
  if (q == 0) wsf[OFF_CS + b * S_ + s] = acc + ba[0];
}

// generic transpose: src[R][Cc] -> dst[Cc][R]
__global__ void __launch_bounds__(256) tkern(const float* __restrict__ src,
                                             float* __restrict__ dst, int R, int Cc) {
  __shared__ float tile[32][33];
  const int c0 = blockIdx.x * 32, r0 = blockIdx.y * 32;
  const int txl = threadIdx.x & 31, ty = threadIdx.x >> 5;
#pragma unroll
  for (int p2 = 0; p2 < 4; ++p2) {
    int r = r0 + ty + p2 * 8, c = c0 + txl;
    if (r < R && c < Cc) tile[ty + p2 * 8][txl] = src[(size_t)r * Cc + c];
  }
  __syncthreads();
#pragma unroll
  for (int p2 = 0; p2 < 4; ++p2) {
    int c = c0 + ty + p2 * 8, r = r0 + txl;
    if (r < R && c < Cc) dst[(size_t)c * R + r] = tile[txl][ty + p2 * 8];
  }
}

// ---------------- main persistent kernel ----------------
__global__ void __launch_bounds__(256) mtad_main(Params p) {
  float* wsf = p.ws;
  int* wsi = (int*)p.ws;
  unsigned* bar = (unsigned*)p.ws;
  const int bk = blockIdx.x;
  const int tx = threadIdx.x;

  __shared__ float rv[NTHR];
  __shared__ int   ri[NTHR];
  __shared__ float rm[NTHR];
  __shared__ float rs[NTHR];
  __shared__ float wlds[S_];
  __shared__ int   sxs;
  __shared__ float shs;
  __shared__ float gp[4][8][B_];
  __shared__ float gg[8][B_];
  __shared__ __align__(16) float sw[2][32][VT];   // WoT tile stage (32 KB)
  __shared__ __align__(16) float sh1[2][32][B_];  // h1T tile stage (8 KB)

  for (int t = 0; t < T_; ++t) {
    const int par = t & 1;
    // ================= Phase A: argmax/LSE reduce + attention =================
    if (bk < B_) {
      const int b = bk;
      int xtok;
      if (t > 0) {
        rv[tx] = wsf[OFF_APV + b * NBLK + tx];
        ri[tx] = wsi[OFF_API + b * NBLK + tx];
        rm[tx] = wsf[OFF_LSM + b * NBLK + tx];
        rs[tx] = wsf[OFF_LSS + b * NBLK + tx];
        __syncthreads();
        if (tx < 64) {
          float av = rv[tx]; int ai = ri[tx]; float m = rm[tx]; float s = rs[tx];
#pragma unroll
          for (int o = 64; o < NTHR; o += 64) {
            float av2 = rv[tx + o]; int ai2 = ri[tx + o];
            if (av2 > av || (av2 == av && ai2 < ai)) { av = av2; ai = ai2; }
            float m2 = rm[tx + o], s2 = rs[tx + o];
            float M = fmaxf(m, m2);
            s = s * expf(m - M) + s2 * expf(m2 - M); m = M;
          }
#pragma unroll
          for (int d = 1; d < 64; d <<= 1) {
            float av2 = __shfl_xor(av, d); int ai2 = __shfl_xor(ai, d);
            float m2 = __shfl_xor(m, d);   float s2 = __shfl_xor(s, d);
            if (av2 > av || (av2 == av && ai2 < ai)) { av = av2; ai = ai2; }
            float M = fmaxf(m, m2);
            s = s * expf(m - M) + s2 * expf(m2 - M); m = M;
          }
          if (tx == 0) { sxs = ai; wsf[OFF_LSE + b] = m + logf(s); }
        }
        __syncthreads();
        xtok = sxs;
      } else {
        xtok = START_TOK;
      }
      // embedding -> inpT rows [0,256)
      wsf[OFF_INPT + tx * B_ + b] = p.embed[(size_t)xtok * E_ + tx];
      // hscore = h1_prev[b] . Wa[0:512]
      const float* h1p = wsf + OFF_H1 + par * (H_ * B_);
      float hs = h1p[tx * B_ + b] * p.Wa[tx] + h1p[(tx + 256) * B_ + b] * p.Wa[tx + 256];
      rv[tx] = hs;
      __syncthreads();
      if (tx < 64) {
        float v = rv[tx] + rv[tx + 64] + rv[tx + 128] + rv[tx + 192];
#pragma unroll
        for (int d = 1; d < 64; d <<= 1) v += __shfl_xor(v, d);
        if (tx == 0) shs = v;
      }
      __syncthreads();
      // scores + softmax over S (tanh-bounded -> no max shift needed)
      if (tx < S_) {
        float sc = tanhf(shs + wsf[OFF_CS + b * S_ + tx]);
        float e = expf(sc);
        float sum = e;
#pragma unroll
        for (int d = 1; d < 64; d <<= 1) sum += __shfl_xor(sum, d);
        float w = e / sum;
        wlds[tx] = w;
        p.out[(size_t)B_ * T_ * V_ + ((size_t)b * T_ + t) * S_ + tx] = w;
      }
      __syncthreads();
      // attend -> inpT rows [256,768)
      {
        float a0 = 0.f, a1 = 0.f;
        const float* cb = p.ctx + (size_t)b * S_ * C_;
#pragma unroll 4
        for (int s2 = 0; s2 < S_; ++s2) {
          float wv = wlds[s2];
          a0 = fmaf(wv, cb[s2 * C_ + tx], a0);
          a1 = fmaf(wv, cb[s2 * C_ + tx + 256], a1);
        }
        wsf[OFF_INPT + (E_ + tx) * B_ + b] = a0;
        wsf[OFF_INPT + (E_ + tx + 256) * B_ + b] = a1;
      }
    }
    gbar(bar);
    // ================= Phase B: GRU layer 0 (2 hidden units / block) =================
    {
      const int j0 = bk * 2;
      const int kq = tx >> 6, c = (tx >> 3) & 7, bq = tx & 7;
      const int slot = c >> 1, jj = c & 1, j = j0 + jj;  // slot: 0=r 1=z 2=nx 3=nh
      const float* h0prev = wsf + OFF_H0 + par * (H_ * B_);
      float acc[4] = {0.f, 0.f, 0.f, 0.f};
      if (slot < 3) {  // input-side: K = 768 over inpT
        const float* wp = wsf + OFF_W0I + slot * 512 + j;
        const float* ap = wsf + OFF_INPT + bq * 4;
        for (int k = kq * 192; k < kq * 192 + 192; ++k) {
          float w = wp[(size_t)k * 1536];
          float4 a = *(const float4*)(ap + k * B_);
          acc[0] = fmaf(a.x, w, acc[0]); acc[1] = fmaf(a.y, w, acc[1]);
          acc[2] = fmaf(a.z, w, acc[2]); acc[3] = fmaf(a.w, w, acc[3]);
        }
      }
      if (slot != 2) { // hidden-side: K = 512 over h0prev
        const int row = (slot == 3 ? 1024 : slot * 512) + j;
        const float* wp = wsf + OFF_W0H + row;
        const float* ap = h0prev + bq * 4;
        for (int k = kq * 128; k < kq * 128 + 128; ++k) {
          float w = wp[(size_t)k * 1536];
          float4 a = *(const float4*)(ap + k * B_);
          acc[0] = fmaf(a.x, w, acc[0]); acc[1] = fmaf(a.y, w, acc[1]);
          acc[2] = fmaf(a.z, w, acc[2]); acc[3] = fmaf(a.w, w, acc[3]);
        }
      }
      *(float4*)&gp[kq][c][bq * 4] = *(float4*)acc;
      __syncthreads();
      {
        const int c2 = tx >> 5, b = tx & 31;
        gg[c2][b] = gp[0][c2][b] + gp[1][c2][b] + gp[2][c2][b] + gp[3][c2][b];
      }
      __syncthreads();
      if (tx < 64) {
        const int jj2 = tx >> 5, b = tx & 31;
        const int j2 = j0 + jj2;
        float r  = sigf(gg[jj2][b]     + p.bih0[j2]        + p.bhh0[j2]);
        float z  = sigf(gg[2 + jj2][b] + p.bih0[512 + j2]  + p.bhh0[512 + j2]);
        float nx = gg[4 + jj2][b] + p.bih0[1024 + j2];
        float nh = gg[6 + jj2][b] + p.bhh0[1024 + j2];
        float n  = tanhf(nx + r * nh);
        float hp = h0prev[j2 * B_ + b];
        float* h0new = wsf + OFF_H0 + (1 - par) * (H_ * B_);
        h0new[j2 * B_ + b] = (1.f - z) * n + z * hp;
      }
    }
    gbar(bar);
    // ================= Phase C: GRU layer 1 =================
    {
      const int j0 = bk * 2;
      const int kq = tx >> 6, c = (tx >> 3) & 7, bq = tx & 7;
      const int slot = c >> 1, jj = c & 1, j = j0 + jj;
      const float* h0new  = wsf + OFF_H0 + (1 - par) * (H_ * B_);
      const float* h1prev = wsf + OFF_H1 + par * (H_ * B_);
      float acc[4] = {0.f, 0.f, 0.f, 0.f};
      if (slot < 3) {  // input-side: K = 512 over h0new
        const float* wp = wsf + OFF_W1I + slot * 512 + j;
        const float* ap = h0new + bq * 4;
        for (int k = kq * 128; k < kq * 128 + 128; ++k) {
          float w = wp[(size_t)k * 1536];
          float4 a = *(const float4*)(ap + k * B_);
          acc[0] = fmaf(a.x, w, acc[0]); acc[1] = fmaf(a.y, w, acc[1]);
          acc[2] = fmaf(a.z, w, acc[2]); acc[3] = fmaf(a.w, w, acc[3]);
        }
      }
      if (slot != 2) { // hidden-side: K = 512 over h1prev
        const int row = (slot == 3 ? 1024 : slot * 512) + j;
        const float* wp = wsf + OFF_W1H + row;
        const float* ap = h1prev + bq * 4;
        for (int k = kq * 128; k < kq * 128 + 128; ++k) {
          float w = wp[(size_t)k * 1536];
          float4 a = *(const float4*)(ap + k * B_);
          acc[0] = fmaf(a.x, w, acc[0]); acc[1] = fmaf(a.y, w, acc[1]);
          acc[2] = fmaf(a.z, w, acc[2]); acc[3] = fmaf(a.w, w, acc[3]);
        }
      }
      *(float4*)&gp[kq][c][bq * 4] = *(float4*)acc;
      __syncthreads();
      {
        const int c2 = tx >> 5, b = tx & 31;
        gg[c2][b] = gp[0][c2][b] + gp[1][c2][b] + gp[2][c2][b] + gp[3][c2][b];
      }
      __syncthreads();
      if (tx < 64) {
        const int jj2 = tx >> 5, b = tx & 31;
        const int j2 = j0 + jj2;
        float r  = sigf(gg[jj2][b]     + p.bih1[j2]        + p.bhh1[j2]);
        float z  = sigf(gg[2 + jj2][b] + p.bih1[512 + j2]  + p.bhh1[512 + j2]);
        float nx = gg[4 + jj2][b] + p.bih1[1024 + j2];
        float nh = gg[6 + jj2][b] + p.bhh1[1024 + j2];
        float n  = tanhf(nx + r * nh);
        float hp = h1prev[j2 * B_ + b];
        float* h1new = wsf + OFF_H1 + (1 - par) * (H_ * B_);
        h1new[j2 * B_ + b] = (1.f - z) * n + z * hp;
      }
    }
    gbar(bar);
    // ================= Phase D: logits GEMM + online lse/argmax =================
    {
      const float* h1cur = wsf + OFF_H1 + (1 - par) * (H_ * B_);
      const float* wot = wsf + OFF_WOT;
      if (bk < NVB) {
        const int v0 = bk * VT;
        const int bt = tx >> 6, vt = tx & 63;  // wave = batch-tile of 8, lane = vocab lane
        float acc[8][2];
#pragma unroll
        for (int i = 0; i < 8; ++i) { acc[i][0] = 0.f; acc[i][1] = 0.f; }
        // stage chunk 0
        {
#pragma unroll
          for (int pp = 0; pp < 4; ++pp) {
            const int f = (pp * NTHR + tx) * 4;
            const int r = f >> 7, cc = f & 127;
            *(float4*)(&sw[0][0][0] + r * VT + cc) =
                *(const float4*)(wot + (size_t)r * V_ + v0 + cc);
          }
          const int f = tx * 4, r = f >> 5, cc = f & 31;
          *(float4*)&sh1[0][r][cc] = *(const float4*)(h1cur + (size_t)r * B_ + cc);
        }
        __syncthreads();
        for (int kc = 0; kc < 16; ++kc) {
          if (kc < 15) {  // stage next chunk into other buffer
            const int nb = (kc + 1) & 1, k0 = (kc + 1) * 32;
#pragma unroll
            for (int pp = 0; pp < 4; ++pp) {
              const int f = (pp * NTHR + tx) * 4;
              const int r = f >> 7, cc = f & 127;
              *(float4*)(&sw[nb][0][0] + r * VT + cc) =
                  *(const float4*)(wot + (size_t)(k0 + r) * V_ + v0 + cc);
            }
            const int f = tx * 4, r = f >> 5, cc = f & 31;
            *(float4*)&sh1[nb][r][cc] = *(const float4*)(h1cur + (size_t)(k0 + r) * B_ + cc);
          }
          const float* swb = &sw[kc & 1][0][0];
          const float* shb = &sh1[kc & 1][0][0];
#pragma unroll 4
          for (int kk = 0; kk < 32; ++kk) {
            float a[8];
            *(float4*)&a[0] = *(const float4*)(shb + kk * B_ + bt * 8);
            *(float4*)&a[4] = *(const float4*)(shb + kk * B_ + bt * 8 + 4);
            const float w0 = swb[kk * VT + vt];
            const float w1 = swb[kk * VT + 64 + vt];
#pragma unroll
            for (int i = 0; i < 8; ++i) {
              acc[i][0] = fmaf(a[i], w0, acc[i][0]);
              acc[i][1] = fmaf(a[i], w1, acc[i][1]);
            }
          }
          __syncthreads();
        }
        // epilogue: + bo, raw logits out, per-(block,b) online partials
        const float bo0 = p.bo[v0 + vt], bo1 = p.bo[v0 + 64 + vt];
        const int b0 = bt * 8;
#pragma unroll
        for (int i = 0; i < 8; ++i) {
          float l0 = acc[i][0] + bo0, l1 = acc[i][1] + bo1;
          float* o = p.out + ((size_t)(b0 + i) * T_ + t) * V_ + v0;
          o[vt] = l0;
          o[64 + vt] = l1;
          float av, m, s; int ai;
          if (l0 >= l1) { av = l0; ai = v0 + vt; } else { av = l1; ai = v0 + 64 + vt; }
          m = fmaxf(l0, l1);
          s = expf(l0 - m) + expf(l1 - m);
#pragma unroll
          for (int d = 1; d < 64; d <<= 1) {
            float av2 = __shfl_xor(av, d); int ai2 = __shfl_xor(ai, d);
            float m2 = __shfl_xor(m, d);   float s2 = __shfl_xor(s, d);
            if (av2 > av || (av2 == av && ai2 < ai)) { av = av2; ai = ai2; }
            float M = fmaxf(m, m2);
            s = s * expf(m - M) + s2 * expf(m2 - M); m = M;
          }
          if (vt == 0) {
            const int b = b0 + i;
            wsf[OFF_APV + b * NBLK + bk] = av;
            wsi[OFF_API + b * NBLK + bk] = ai;
            wsf[OFF_LSM + b * NBLK + bk] = m;
            wsf[OFF_LSS + b * NBLK + bk] = s;
          }
        }
        // fold in log-softmax fix for step t-1 (overlapped with compute phase)
        if (t > 0) {
#pragma unroll
          for (int i = 0; i < 8; ++i) {
            const int b = b0 + i;
            const float lse = wsf[OFF_LSE + b];
            float* o = p.out + ((size_t)b * T_ + (t - 1)) * V_ + v0;
            o[vt] -= lse;
            o[64 + vt] -= lse;
          }
        }
      } else {
        // ghost blocks: write neutral partials so phase-A reduce is well-defined
        if (tx < B_) {
          wsf[OFF_APV + tx * NBLK + bk] = -__builtin_inff();
          wsi[OFF_API + tx * NBLK + bk] = 0x7fffffff;
          wsf[OFF_LSM + tx * NBLK + bk] = -__builtin_inff();
          wsf[OFF_LSS + tx * NBLK + bk] = 0.f;
        }
      }
    }
    if (t < T_ - 1) gbar(bar);
  }
}

// ---------------- epilogue: log-softmax fix for last step ----------------
__global__ void __launch_bounds__(256) mtad_epi(float* __restrict__ out,
                                                const float* __restrict__ wsf) {
  const int b = blockIdx.x, tx = threadIdx.x;
  __shared__ float rm[NTHR], rs[NTHR];
  __shared__ float slse;
  rm[tx] = wsf[OFF_LSM + b * NBLK + tx];
  rs[tx] = wsf[OFF_LSS + b * NBLK + tx];
  __syncthreads();
  if (tx < 64) {
    float m = rm[tx], s = rs[tx];
#pragma unroll
    for (int o = 64; o < NTHR; o += 64) {
      float m2 = rm[tx + o], s2 = rs[tx + o];
      float M = fmaxf(m, m2);
      s = s * expf(m - M) + s2 * expf(m2 - M); m = M;
    }
#pragma unroll
    for (int d = 1; d < 64; d <<= 1) {
      float m2 = __shfl_xor(m, d), s2 = __shfl_xor(s, d);
      float M = fmaxf(m, m2);
      s = s * expf(m - M) + s2 * expf(m2 - M); m = M;
    }
    if (tx == 0) slse = m + logf(s);
  }
  __syncthreads();
  const float lse = slse;
  float* o = out + ((size_t)b * T_ + (T_ - 1)) * V_;
  for (int v = tx; v < V_; v += 256) o[v] -= lse;
}

// ---------------- host launch ----------------
extern "C" void kernel_launch(void* const* d_in, const int* in_sizes, int n_in,
                              void* d_out, int out_size, void* d_ws, size_t ws_size,
                              hipStream_t stream) {
  (void)in_sizes; (void)n_in; (void)out_size;
  if (ws_size < (size_t)WS_FLOATS * sizeof(float)) return;  // workspace too small: clean fail

  const float* ctx   = (const float*)d_in[0];
  // d_in[1] = max_len (scalar, == 32, hardcoded)
  const float* embed = (const float*)d_in[2];
  const float* Wa    = (const float*)d_in[3];
  const float* ba    = (const float*)d_in[4];
  const float* Wih0  = (const float*)d_in[5];
  const float* Whh0  = (const float*)d_in[6];
  const float* bih0  = (const float*)d_in[7];
  const float* bhh0  = (const float*)d_in[8];
  const float* Wih1  = (const float*)d_in[9];
  const float* Whh1  = (const float*)d_in[10];
  const float* bih1  = (const float*)d_in[11];
  const float* bhh1  = (const float*)d_in[12];
  const float* Wo    = (const float*)d_in[13];
  const float* bo    = (const float*)d_in[14];
  float* ws  = (float*)d_ws;
  float* out = (float*)d_out;

  zero_k<<<dim3(256), dim3(256), 0, stream>>>(ws);
  cscore_k<<<dim3(32), dim3(256), 0, stream>>>(ctx, Wa, ba, ws);
  // weight transposes into workspace
  tkern<<<dim3(24, 48),   dim3(256), 0, stream>>>(Wih0, ws + OFF_W0I, 1536, 768);
  tkern<<<dim3(16, 48),   dim3(256), 0, stream>>>(Whh0, ws + OFF_W0H, 1536, 512);
  tkern<<<dim3(16, 48),   dim3(256), 0, stream>>>(Wih1, ws + OFF_W1I, 1536, 512);
  tkern<<<dim3(16, 48),   dim3(256), 0, stream>>>(Whh1, ws + OFF_W1H, 1536, 512);
  tkern<<<dim3(16, 1000), dim3(256), 0, stream>>>(Wo,   ws + OFF_WOT, 32000, 512);

  Params p;
  p.ctx = ctx; p.embed = embed; p.Wa = Wa;
  p.bih0 = bih0; p.bhh0 = bhh0; p.bih1 = bih1; p.bhh1 = bhh1;
  p.bo = bo; p.ws = ws; p.out = out;
  mtad_main<<<dim3(NBLK), dim3(NTHR), 0, stream>>>(p);

  mtad_epi<<<dim3(32), dim3(256), 0, stream>>>(out, ws);
}

// Round 2
// 4660.219 us; speedup vs baseline: 1.6800x; 1.6800x over previous
//
#include <hip/hip_runtime.h>

// ---------------- problem constants ----------------
#define B_ 32
#define S_ 64
#define C_ 512
#define E_ 256
#define H_ 512
#define V_ 32000
#define T_ 32
#define NBLK 256       // grid blocks (persistent kernel)
#define NTHR 512       // threads per block (8 waves)
#define NVB 250        // blocks active in scan phase (250*128 = 32000)
#define VT 128         // vocab tile per block
#define START_TOK 1

// ---------------- workspace layout (float offsets) ----------------
#define OFF_BAR   0         // 2 uints: barrier count, generation
#define OFF_CS    64        // cscore[32][64]
#define OFF_LSEA  2112      // lse_all[32 t][32 b]
#define OFF_APV   3136      // argmax partial value [32][256]
#define OFF_API   11328     // argmax partial index [32][256] (int)
#define OFF_LSM   19520     // lse partial max [32][256]
#define OFF_LSS   27712     // lse partial sum [32][256]
#define OFF_INPT  35904     // inpT[768][32]
#define OFF_H0    60480     // h0T[2][512][32] ping-pong
#define OFF_H1    93248     // h1T[2][512][32] ping-pong
#define OFF_H1BF  126016    // ushort[1024][512]  (row M = t*32+b)
#define OFF_WOBF  388160    // ushort[32000][512]
#define WS_FLOATS 8580160   // ~34.3 MB

struct Params {
  const float* ctx; const float* embed; const float* Wa;
  const float* Wih0; const float* Whh0; const float* bih0; const float* bhh0;
  const float* Wih1; const float* Whh1; const float* bih1; const float* bhh1;
  const float* Wo; const float* bo;
  float* ws; float* out;
};

__device__ __forceinline__ float sigf(float x) { return 1.0f / (1.0f + expf(-x)); }

__device__ __forceinline__ unsigned short f2bf(float f) {  // RNE f32->bf16
  unsigned u = __builtin_bit_cast(unsigned, f);
  unsigned r = (u + 0x7FFFu + ((u >> 16) & 1u)) >> 16;
  return (unsigned short)r;
}

__device__ __forceinline__ void lse_merge(float& m, float& s, float m2, float s2) {
  float M = fmaxf(m, m2);
  s = s * expf(m - M) + s2 * expf(m2 - M);
  m = M;
}

// -------- device-scope grid barrier (all NBLK blocks co-resident) --------
__device__ __forceinline__ void gbar(unsigned* bar) {
  __syncthreads();
  if (threadIdx.x == 0) {
    __builtin_amdgcn_fence(__ATOMIC_RELEASE, "agent");
    unsigned g = __hip_atomic_load(bar + 1, __ATOMIC_RELAXED, __HIP_MEMORY_SCOPE_AGENT);
    unsigned a = __hip_atomic_fetch_add(bar, 1u, __ATOMIC_RELAXED, __HIP_MEMORY_SCOPE_AGENT);
    if (a == NBLK - 1) {
      __hip_atomic_store(bar, 0u, __ATOMIC_RELAXED, __HIP_MEMORY_SCOPE_AGENT);
      __hip_atomic_store(bar + 1, g + 1u, __ATOMIC_RELEASE, __HIP_MEMORY_SCOPE_AGENT);
    } else {
      while (__hip_atomic_load(bar + 1, __ATOMIC_RELAXED, __HIP_MEMORY_SCOPE_AGENT) == g) {
        __builtin_amdgcn_s_sleep(8);
      }
    }
    __builtin_amdgcn_fence(__ATOMIC_ACQUIRE, "agent");
  }
  __syncthreads();
}

// ---------------- prologue kernels ----------------
__global__ void __launch_bounds__(256) zero_k(float* wsf) {
  const unsigned i = blockIdx.x * 256u + threadIdx.x;
  if (i < 2u) ((unsigned*)wsf)[OFF_BAR + i] = 0u;
  if (i < 65536u) wsf[OFF_H0 + i] = 0.0f;   // h0T[2] + h1T[2] contiguous
}

__global__ void __launch_bounds__(256) cscore_k(const float* __restrict__ ctx,
                                                const float* __restrict__ Wa,
                                                const float* __restrict__ ba,
                                                float* __restrict__ wsf) {
  const int b = blockIdx.x;
  const int s = threadIdx.x >> 2, q = threadIdx.x & 3;
  const float* cp = ctx + ((size_t)b * S_ + s) * C_ + q * 128;
  const float* wp = Wa + H_ + q * 128;     // context half of Wa
  float acc = 0.f;
#pragma unroll 8
  for (int k = 0; k < 128; ++k) acc = fmaf(cp[k], wp[k], acc);
  acc += __shfl_xor(acc, 1);
  acc += __shfl_xor(acc, 2);
  if (q == 0) wsf[OFF_CS + b * S_ + s] = acc + ba[0];
}

__global__ void __launch_bounds__(256) cvt_wobf(const float* __restrict__ wo,
                                                unsigned short* __restrict__ dst) {
  const size_t i = ((size_t)blockIdx.x * 256u + threadIdx.x) * 4;
  float4 v = *(const float4*)(wo + i);
  ushort4 o;
  o.x = f2bf(v.x); o.y = f2bf(v.y); o.z = f2bf(v.z); o.w = f2bf(v.w);
  *(ushort4*)(dst + i) = o;
}

// ---------------- main persistent kernel ----------------
__global__ void __launch_bounds__(NTHR) mtad_main(Params p) {
  float* wsf = p.ws;
  int* wsi = (int*)p.ws;
  unsigned* bar = (unsigned*)p.ws;
  unsigned short* h1bf = (unsigned short*)(p.ws + OFF_H1BF);
  const int bk = blockIdx.x;
  const int tx = threadIdx.x;

  __shared__ float rv[NTHR];
  __shared__ int   ri[NTHR];
  __shared__ float rm[NTHR];
  __shared__ float rs[NTHR];
  __shared__ float wlds[S_];
  __shared__ float attp[4][128];
  __shared__ int   sxs;
  __shared__ float shs;
  __shared__ __align__(16) float gp[8][8][B_];
  __shared__ float gg[8][B_];
  __shared__ __align__(16) float sw[2][32][130];    // Wo chunk, [kk][v] padded
  __shared__ __align__(16) float sh1c[2][32][B_];   // h1 chunk [kk][b]

// stage Wo chunk kc into buffer ci (transpose [v][k] -> [kk][v])
#define STAGE_W(ci, kc) {                                                   \
    const int v = tx >> 2, s0 = (tx & 3) * 2;                               \
    const float* wrow = p.Wo + (size_t)(v0 + v) * H_ + (kc) * 32;           \
    _Pragma("unroll")                                                       \
    for (int s = s0; s < s0 + 2; ++s) {                                     \
      float4 wv = *(const float4*)(wrow + s * 4);                           \
      sw[ci][s*4+0][v] = wv.x; sw[ci][s*4+1][v] = wv.y;                     \
      sw[ci][s*4+2][v] = wv.z; sw[ci][s*4+3][v] = wv.w;                     \
    } }
#define STAGE_H(ci, kc) {                                                   \
    if (tx < 256) {                                                         \
      const int k = tx >> 3, col = (tx & 7) * 4;                            \
      *(float4*)&sh1c[ci][k][col] =                                         \
          *(const float4*)(h1cur + (size_t)((kc) * 32 + k) * B_ + col);     \
    } }

  for (int t = 0; t < T_; ++t) {
    const int par = t & 1;
    // ================= Phase A: argmax/LSE reduce + attention =================
    if (bk < 128) {
      const int b = bk >> 2, quarter = bk & 3;
      int xtok;
      if (t > 0) {
        if (tx < 256) {
          rv[tx] = wsf[OFF_APV + b * 256 + tx];
          ri[tx] = wsi[OFF_API + b * 256 + tx];
          rm[tx] = wsf[OFF_LSM + b * 256 + tx];
          rs[tx] = wsf[OFF_LSS + b * 256 + tx];
        }
        __syncthreads();
        if (tx < 64) {
          float av = rv[tx]; int ai = ri[tx]; float m = rm[tx]; float s = rs[tx];
#pragma unroll
          for (int o = 64; o < 256; o += 64) {
            float av2 = rv[tx + o]; int ai2 = ri[tx + o];
            if (av2 > av || (av2 == av && ai2 < ai)) { av = av2; ai = ai2; }
            lse_merge(m, s, rm[tx + o], rs[tx + o]);
          }
#pragma unroll
          for (int d = 1; d < 64; d <<= 1) {
            float av2 = __shfl_xor(av, d); int ai2 = __shfl_xor(ai, d);
            float m2 = __shfl_xor(m, d);   float s2 = __shfl_xor(s, d);
            if (av2 > av || (av2 == av && ai2 < ai)) { av = av2; ai = ai2; }
            lse_merge(m, s, m2, s2);
          }
          if (tx == 0) {
            sxs = ai;
            if (quarter == 0) wsf[OFF_LSEA + (t - 1) * B_ + b] = m + logf(s);
          }
        }
        __syncthreads();
        xtok = sxs;
      } else {
        xtok = START_TOK;
      }
      // embedding -> inpT rows [0,256)
      if (quarter == 0 && tx < 256)
        wsf[OFF_INPT + tx * B_ + b] = p.embed[(size_t)xtok * E_ + tx];
      // hscore = h1_prev[b] . Wa[0:512]
      const float* h1p = wsf + OFF_H1 + par * (H_ * B_);
      rv[tx] = h1p[tx * B_ + b] * p.Wa[tx];
      __syncthreads();
      if (tx < 64) {
        float v = 0.f;
#pragma unroll
        for (int o = 0; o < NTHR; o += 64) v += rv[tx + o];
#pragma unroll
        for (int d = 1; d < 64; d <<= 1) v += __shfl_xor(v, d);
        if (tx == 0) shs = v;
      }
      __syncthreads();
      // scores + softmax over S (tanh-bounded -> no max shift needed)
      if (tx < S_) {
        float sc = tanhf(shs + wsf[OFF_CS + b * S_ + tx]);
        float e = expf(sc);
        float sum = e;
#pragma unroll
        for (int d = 1; d < 64; d <<= 1) sum += __shfl_xor(sum, d);
        float w = e / sum;
        wlds[tx] = w;
        if (quarter == 0)
          p.out[(size_t)B_ * T_ * V_ + ((size_t)b * T_ + t) * S_ + tx] = w;
      }
      __syncthreads();
      // attend (this quarter's 128 c's, s split 4 ways) -> inpT rows [256,768)
      {
        const int cq = tx & 127, sq = tx >> 7;
        const float* cb = p.ctx + ((size_t)b * S_ + sq * 16) * C_ + quarter * 128 + cq;
        float a0 = 0.f;
#pragma unroll
        for (int s2 = 0; s2 < 16; ++s2)
          a0 = fmaf(wlds[sq * 16 + s2], cb[(size_t)s2 * C_], a0);
        attp[sq][cq] = a0;
      }
      __syncthreads();
      if (tx < 128)
        wsf[OFF_INPT + (E_ + quarter * 128 + tx) * B_ + b] =
            attp[0][tx] + attp[1][tx] + attp[2][tx] + attp[3][tx];
    }
    gbar(bar);
    // ================= Phase B: GRU layer 0 =================
    {
      const int j0 = bk * 2;
      const int kq = tx >> 6, c = (tx >> 3) & 7, bq = tx & 7;
      const int slot = c >> 1, jj = c & 1, j = j0 + jj;  // slot: 0=r 1=z 2=nx 3=nh
      const float* h0prev = wsf + OFF_H0 + par * (H_ * B_);
      float acc[4] = {0.f, 0.f, 0.f, 0.f};
      if (slot < 3) {  // input-side: K = 768 over inpT
        const float* wp = p.Wih0 + (size_t)(slot * H_ + j) * 768;
        const float* ap = wsf + OFF_INPT + bq * 4;
#pragma unroll 4
        for (int k = kq * 96; k < kq * 96 + 96; ++k) {
          float w = wp[k];
          float4 a = *(const float4*)(ap + k * B_);
          acc[0] = fmaf(a.x, w, acc[0]); acc[1] = fmaf(a.y, w, acc[1]);
          acc[2] = fmaf(a.z, w, acc[2]); acc[3] = fmaf(a.w, w, acc[3]);
        }
      }
      if (slot != 2) { // hidden-side: K = 512 over h0prev
        const int row = (slot == 3 ? 1024 : slot * H_) + j;
        const float* wp = p.Whh0 + (size_t)row * H_;
        const float* ap = h0prev + bq * 4;
#pragma unroll 4
        for (int k = kq * 64; k < kq * 64 + 64; ++k) {
          float w = wp[k];
          float4 a = *(const float4*)(ap + k * B_);
          acc[0] = fmaf(a.x, w, acc[0]); acc[1] = fmaf(a.y, w, acc[1]);
          acc[2] = fmaf(a.z, w, acc[2]); acc[3] = fmaf(a.w, w, acc[3]);
        }
      }
      *(float4*)&gp[kq][c][bq * 4] = *(float4*)acc;
      __syncthreads();
      if (tx < 256) {
        const int c2 = tx >> 5, b = tx & 31;
        float s = 0.f;
#pragma unroll
        for (int q = 0; q < 8; ++q) s += gp[q][c2][b];
        gg[c2][b] = s;
      }
      __syncthreads();
      if (tx < 64) {
        const int jj2 = tx >> 5, b = tx & 31;
        const int j2 = j0 + jj2;
        float r  = sigf(gg[jj2][b]     + p.bih0[j2]       + p.bhh0[j2]);
        float z  = sigf(gg[2 + jj2][b] + p.bih0[H_ + j2]  + p.bhh0[H_ + j2]);
        float nx = gg[4 + jj2][b] + p.bih0[1024 + j2];
        float nh = gg[6 + jj2][b] + p.bhh0[1024 + j2];
        float n  = tanhf(nx + r * nh);
        float hp = h0prev[j2 * B_ + b];
        float* h0new = wsf + OFF_H0 + (1 - par) * (H_ * B_);
        h0new[j2 * B_ + b] = (1.f - z) * n + z * hp;
      }
    }
    gbar(bar);
    // ================= Phase C: GRU layer 1 (+ Wo chunk-0 prefetch) ==========
    {
      const int j0 = bk * 2;
      const int kq = tx >> 6, c = (tx >> 3) & 7, bq = tx & 7;
      const int slot = c >> 1, jj = c & 1, j = j0 + jj;
      const float* h0new  = wsf + OFF_H0 + (1 - par) * (H_ * B_);
      const float* h1prev = wsf + OFF_H1 + par * (H_ * B_);
      float acc[4] = {0.f, 0.f, 0.f, 0.f};
      if (slot < 3) {  // input-side: K = 512 over h0new
        const float* wp = p.Wih1 + (size_t)(slot * H_ + j) * H_;
        const float* ap = h0new + bq * 4;
#pragma unroll 4
        for (int k = kq * 64; k < kq * 64 + 64; ++k) {
          float w = wp[k];
          float4 a = *(const float4*)(ap + k * B_);
          acc[0] = fmaf(a.x, w, acc[0]); acc[1] = fmaf(a.y, w, acc[1]);
          acc[2] = fmaf(a.z, w, acc[2]); acc[3] = fmaf(a.w, w, acc[3]);
        }
      }
      if (slot != 2) { // hidden-side: K = 512 over h1prev
        const int row = (slot == 3 ? 1024 : slot * H_) + j;
        const float* wp = p.Whh1 + (size_t)row * H_;
        const float* ap = h1prev + bq * 4;
#pragma unroll 4
        for (int k = kq * 64; k < kq * 64 + 64; ++k) {
          float w = wp[k];
          float4 a = *(const float4*)(ap + k * B_);
          acc[0] = fmaf(a.x, w, acc[0]); acc[1] = fmaf(a.y, w, acc[1]);
          acc[2] = fmaf(a.z, w, acc[2]); acc[3] = fmaf(a.w, w, acc[3]);
        }
      }
      *(float4*)&gp[kq][c][bq * 4] = *(float4*)acc;
      // prefetch Wo chunk 0 for phase D into sw[0] (Wo is step-invariant)
      if (bk < NVB) {
        const int v0 = bk * VT;
        STAGE_W(0, 0);
      }
      __syncthreads();
      if (tx < 256) {
        const int c2 = tx >> 5, b = tx & 31;
        float s = 0.f;
#pragma unroll
        for (int q = 0; q < 8; ++q) s += gp[q][c2][b];
        gg[c2][b] = s;
      }
      __syncthreads();
      if (tx < 64) {
        const int jj2 = tx >> 5, b = tx & 31;
        const int j2 = j0 + jj2;
        float r  = sigf(gg[jj2][b]     + p.bih1[j2]       + p.bhh1[j2]);
        float z  = sigf(gg[2 + jj2][b] + p.bih1[H_ + j2]  + p.bhh1[H_ + j2]);
        float nx = gg[4 + jj2][b] + p.bih1[1024 + j2];
        float nh = gg[6 + jj2][b] + p.bhh1[1024 + j2];
        float n  = tanhf(nx + r * nh);
        float hp = h1prev[j2 * B_ + b];
        float hnew = (1.f - z) * n + z * hp;
        float* h1new = wsf + OFF_H1 + (1 - par) * (H_ * B_);
        h1new[j2 * B_ + b] = hnew;
        h1bf[((size_t)t * B_ + b) * H_ + j2] = f2bf(hnew);  // for final GEMM
      }
    }
    gbar(bar);
    // ========== Phase D: logits scan (online max/lse/argmax, no writes) ======
    {
      const float* h1cur = wsf + OFF_H1 + (1 - par) * (H_ * B_);
      if (bk < NVB) {
        const int v0 = bk * VT;
        float acc[4][2] = {};
        STAGE_H(0, 0);            // sw[0] already prefetched in phase C
        __syncthreads();
        for (int kc = 0; kc < 16; ++kc) {
          const int cur = kc & 1;
          if (kc < 15) {
            STAGE_W(cur ^ 1, kc + 1);
            STAGE_H(cur ^ 1, kc + 1);
          }
          const int bt = tx >> 6, vt = tx & 63, b0 = bt * 4;
#pragma unroll
          for (int kk = 0; kk < 32; ++kk) {
            float4 a = *(const float4*)&sh1c[cur][kk][b0];
            float w0 = sw[cur][kk][vt];
            float w1 = sw[cur][kk][64 + vt];
            acc[0][0] = fmaf(a.x, w0, acc[0][0]); acc[0][1] = fmaf(a.x, w1, acc[0][1]);
            acc[1][0] = fmaf(a.y, w0, acc[1][0]); acc[1][1] = fmaf(a.y, w1, acc[1][1]);
            acc[2][0] = fmaf(a.z, w0, acc[2][0]); acc[2][1] = fmaf(a.z, w1, acc[2][1]);
            acc[3][0] = fmaf(a.w, w0, acc[3][0]); acc[3][1] = fmaf(a.w, w1, acc[3][1]);
          }
          __syncthreads();
        }
        // epilogue: + bo, per-(block,b) online partials (wave bt owns b0..b0+3)
        const int bt = tx >> 6, vt = tx & 63, b0 = bt * 4;
        const float bo0 = p.bo[v0 + vt], bo1 = p.bo[v0 + 64 + vt];
#pragma unroll
        for (int i = 0; i < 4; ++i) {
          float l0 = acc[i][0] + bo0, l1 = acc[i][1] + bo1;
          float av, m, s; int ai;
          if (l0 >= l1) { av = l0; ai = v0 + vt; } else { av = l1; ai = v0 + 64 + vt; }
          m = fmaxf(l0, l1);
          s = expf(l0 - m) + expf(l1 - m);
#pragma unroll
          for (int d = 1; d < 64; d <<= 1) {
            float av2 = __shfl_xor(av, d); int ai2 = __shfl_xor(ai, d);
            float m2 = __shfl_xor(m, d);   float s2 = __shfl_xor(s, d);
            if (av2 > av || (av2 == av && ai2 < ai)) { av = av2; ai = ai2; }
            lse_merge(m, s, m2, s2);
          }
          if (vt == 0) {
            const int b = b0 + i;
            wsf[OFF_APV + b * 256 + bk] = av;
            wsi[OFF_API + b * 256 + bk] = ai;
            wsf[OFF_LSM + b * 256 + bk] = m;
            wsf[OFF_LSS + b * 256 + bk] = s;
          }
        }
      } else {
        // ghost blocks: neutral partials
        if (tx < B_) {
          wsf[OFF_APV + tx * 256 + bk] = -__builtin_inff();
          wsi[OFF_API + tx * 256 + bk] = 0x7fffffff;
          wsf[OFF_LSM + tx * 256 + bk] = -__builtin_inff();
          wsf[OFF_LSS + tx * 256 + bk] = 0.f;
        }
      }
    }
    if (t < T_ - 1) gbar(bar);
  }
#undef STAGE_W
#undef STAGE_H
}

// ---------------- epilogue: lse for last step ----------------
__global__ void __launch_bounds__(256) epi_lse(float* __restrict__ wsf) {
  const int b = blockIdx.x, tx = threadIdx.x;
  __shared__ float rm[256], rs[256];
  rm[tx] = wsf[OFF_LSM + b * 256 + tx];
  rs[tx] = wsf[OFF_LSS + b * 256 + tx];
  __syncthreads();
  if (tx < 64) {
    float m = rm[tx], s = rs[tx];
#pragma unroll
    for (int o = 64; o < 256; o += 64) lse_merge(m, s, rm[tx + o], rs[tx + o]);
#pragma unroll
    for (int d = 1; d < 64; d <<= 1) {
      float m2 = __shfl_xor(m, d), s2 = __shfl_xor(s, d);
      lse_merge(m, s, m2, s2);
    }
    if (tx == 0) wsf[OFF_LSEA + 31 * B_ + b] = m + logf(s);
  }
}

// ---------------- final batched logp GEMM (bf16 MFMA) ----------------
typedef __attribute__((ext_vector_type(8))) short bf16x8;
typedef __attribute__((ext_vector_type(4))) float f32x4;

__global__ void __launch_bounds__(256) gemm_logp(const unsigned short* __restrict__ h1bf,
                                                 const unsigned short* __restrict__ wobf,
                                                 const float* __restrict__ bo,
                                                 const float* __restrict__ lsea,
                                                 float* __restrict__ out) {
  __shared__ __align__(16) unsigned short As[2][128 * 40];  // rows padded to 80B
  __shared__ __align__(16) unsigned short Bs[2][128 * 40];
  const int tx = threadIdx.x;
  const int v0 = blockIdx.x * 128, m0 = blockIdx.y * 128;
  const int w = tx >> 6, l = tx & 63;
  const int wm = w >> 1, wn = w & 1;
  f32x4 acc[4][4];
#pragma unroll
  for (int i = 0; i < 4; ++i)
#pragma unroll
    for (int j = 0; j < 4; ++j) acc[i][j] = (f32x4){0.f, 0.f, 0.f, 0.f};

#define GSTAGE(ci, kc) {                                                        \
    _Pragma("unroll")                                                           \
    for (int e = 0; e < 2; ++e) {                                               \
      const int seg = tx * 2 + e, row = seg >> 2, s = seg & 3;                  \
      *(uint4*)&As[ci][row * 40 + s * 8] =                                      \
          *(const uint4*)(h1bf + (size_t)(m0 + row) * H_ + (kc) * 32 + s * 8);  \
      *(uint4*)&Bs[ci][row * 40 + s * 8] =                                      \
          *(const uint4*)(wobf + (size_t)(v0 + row) * H_ + (kc) * 32 + s * 8);  \
    } }

  GSTAGE(0, 0);
  __syncthreads();
  for (int kc = 0; kc < 16; ++kc) {
    const int cur = kc & 1;
    if (kc < 15) GSTAGE(cur ^ 1, kc + 1);
    const int lk = (l >> 4) * 8, lr = l & 15;
    bf16x8 af[4], bf[4];
#pragma unroll
    for (int f = 0; f < 4; ++f) {
      af[f] = *(const bf16x8*)&As[cur][(wm * 64 + f * 16 + lr) * 40 + lk];
      bf[f] = *(const bf16x8*)&Bs[cur][(wn * 64 + f * 16 + lr) * 40 + lk];
    }
#pragma unroll
    for (int fm = 0; fm < 4; ++fm)
#pragma unroll
      for (int fn = 0; fn < 4; ++fn)
        acc[fm][fn] = __builtin_amdgcn_mfma_f32_16x16x32_bf16(af[fm], bf[fn], acc[fm][fn], 0, 0, 0);
    __syncthreads();
  }
#undef GSTAGE
  // epilogue: D[row][col]: col = lane&15, row = (lane>>4)*4 + reg  (m89-verified)
  const int lr = l & 15, lq = l >> 4;
#pragma unroll
  for (int fm = 0; fm < 4; ++fm) {
#pragma unroll
    for (int fn = 0; fn < 4; ++fn) {
      const int v = v0 + wn * 64 + fn * 16 + lr;
      const float bov = bo[v];
#pragma unroll
      for (int r = 0; r < 4; ++r) {
        const int M = m0 + wm * 64 + fm * 16 + lq * 4 + r;
        const int tt = M >> 5, b = M & 31;
        out[((size_t)b * T_ + tt) * (size_t)V_ + v] = acc[fm][fn][r] + bov - lsea[tt * B_ + b];
      }
    }
  }
}

// ---------------- host launch ----------------
extern "C" void kernel_launch(void* const* d_in, const int* in_sizes, int n_in,
                              void* d_out, int out_size, void* d_ws, size_t ws_size,
                              hipStream_t stream) {
  (void)in_sizes; (void)n_in; (void)out_size;
  if (ws_size < (size_t)WS_FLOATS * sizeof(float)) return;  // workspace too small: clean fail

  const float* ctx   = (const float*)d_in[0];
  // d_in[1] = max_len (scalar, == 32, hardcoded)
  const float* embed = (const float*)d_in[2];
  const float* Wa    = (const float*)d_in[3];
  const float* ba    = (const float*)d_in[4];
  const float* Wih0  = (const float*)d_in[5];
  const float* Whh0  = (const float*)d_in[6];
  const float* bih0  = (const float*)d_in[7];
  const float* bhh0  = (const float*)d_in[8];
  const float* Wih1  = (const float*)d_in[9];
  const float* Whh1  = (const float*)d_in[10];
  const float* bih1  = (const float*)d_in[11];
  const float* bhh1  = (const float*)d_in[12];
  const float* Wo    = (const float*)d_in[13];
  const float* bo    = (const float*)d_in[14];
  float* ws  = (float*)d_ws;
  float* out = (float*)d_out;

  zero_k<<<dim3(256), dim3(256), 0, stream>>>(ws);
  cscore_k<<<dim3(32), dim3(256), 0, stream>>>(ctx, Wa, ba, ws);
  cvt_wobf<<<dim3(16000), dim3(256), 0, stream>>>(Wo, (unsigned short*)(ws + OFF_WOBF));

  Params p;
  p.ctx = ctx; p.embed = embed; p.Wa = Wa;
  p.Wih0 = Wih0; p.Whh0 = Whh0; p.bih0 = bih0; p.bhh0 = bhh0;
  p.Wih1 = Wih1; p.Whh1 = Whh1; p.bih1 = bih1; p.bhh1 = bhh1;
  p.Wo = Wo; p.bo = bo; p.ws = ws; p.out = out;
  mtad_main<<<dim3(NBLK), dim3(NTHR), 0, stream>>>(p);

  epi_lse<<<dim3(32), dim3(256), 0, stream>>>(ws);
  gemm_logp<<<dim3(250, 8), dim3(256), 0, stream>>>(
      (const unsigned short*)(ws + OFF_H1BF), (const unsigned short*)(ws + OFF_WOBF),
      bo, ws + OFF_LSEA, out);
}

// Round 3
// 4267.602 us; speedup vs baseline: 1.8345x; 1.0920x over previous
//
#include <hip/hip_runtime.h>

// ---------------- problem constants ----------------
#define B_ 32
#define S_ 64
#define C_ 512
#define E_ 256
#define H_ 512
#define V_ 32000
#define T_ 32
#define NBLK 256       // grid blocks (persistent kernel)
#define NTHR 512       // threads per block (8 waves)
#define NVB 250        // blocks active in scan phase (250*128 = 32000)
#define VT 128         // vocab tile per block
#define START_TOK 1
#define DELTA 0.0625f  // refine margin (bf16 logit error ~0.004)

// ---------------- workspace layout (float offsets) ----------------
#define OFF_BAR  0          // 2 uints
#define OFF_CS   64         // cscore[32][64]
#define OFF_LSEA 2112       // lse[32 t][32 b]
#define OFF_A2V  3136       // top2 cand value [32 b][512]
#define OFF_A2I  19520      // top2 cand index [32 b][512] (int)
#define OFF_LSM  35904      // lse partial max [32][256]
#define OFF_LSS  44096      // lse partial sum [32][256]
#define OFF_INP  52288      // inpR[32 b][768]
#define OFF_H0   76864      // h0R[2][32 b][512] ping-pong
#define OFF_H1   109632     // h1R[2][32 b][512] ping-pong
#define OFF_H1BF 142400     // ushort[32 t * 32 b][512]
#define OFF_WOBF 404544     // ushort[32000][512]
#define WS_FLOATS 8596544   // ~34.4 MB

typedef __attribute__((ext_vector_type(8))) short bf16x8;
typedef __attribute__((ext_vector_type(4))) float f32x4;

struct Params {
  const float* ctx; const float* embed; const float* Wa;
  const float* Wih0; const float* Whh0; const float* bih0; const float* bhh0;
  const float* Wih1; const float* Whh1; const float* bih1; const float* bhh1;
  const float* Wo; const float* bo;
  float* ws; float* out;
};

__device__ __forceinline__ float sigf(float x) { return 1.0f / (1.0f + expf(-x)); }

__device__ __forceinline__ unsigned short f2bf(float f) {  // RNE f32->bf16
  unsigned u = __builtin_bit_cast(unsigned, f);
  unsigned r = (u + 0x7FFFu + ((u >> 16) & 1u)) >> 16;
  return (unsigned short)r;
}

__device__ __forceinline__ void lse_merge(float& m, float& s, float m2, float s2) {
  float M = fmaxf(m, m2);
  s = s * expf(m - M) + s2 * expf(m2 - M);
  m = M;
}

// ---- coherent (L2-bypass, L3-serialized) scalar access for mutable data ----
__device__ __forceinline__ float ld_cf(const float* p) {
  return __hip_atomic_load(p, __ATOMIC_RELAXED, __HIP_MEMORY_SCOPE_AGENT);
}
__device__ __forceinline__ void st_cf(float* p, float v) {
  __hip_atomic_store(p, v, __ATOMIC_RELAXED, __HIP_MEMORY_SCOPE_AGENT);
}
__device__ __forceinline__ int ld_ci(const int* p) {
  return __hip_atomic_load(p, __ATOMIC_RELAXED, __HIP_MEMORY_SCOPE_AGENT);
}
__device__ __forceinline__ void st_ci(int* p, int v) {
  __hip_atomic_store(p, v, __ATOMIC_RELAXED, __HIP_MEMORY_SCOPE_AGENT);
}

// -------- grid barrier WITHOUT L2-invalidating fences --------
// All mutable cross-block data uses sc0/sc1 (coherent) ops, so the barrier
// only needs: drain own VMEM (done by compiler before s_barrier), ordered
// count/gen atomics at the L3 coherence point. Clean L2 lines (weights) survive.
__device__ __forceinline__ void gbar(unsigned* bar) {
  __syncthreads();
  if (threadIdx.x == 0) {
    asm volatile("s_waitcnt vmcnt(0) lgkmcnt(0)" ::: "memory");
    unsigned g = __hip_atomic_load(bar + 1, __ATOMIC_RELAXED, __HIP_MEMORY_SCOPE_AGENT);
    asm volatile("s_waitcnt vmcnt(0)" ::: "memory");   // g fetched before add lands
    unsigned a = __hip_atomic_fetch_add(bar, 1u, __ATOMIC_RELAXED, __HIP_MEMORY_SCOPE_AGENT);
    if (a == NBLK - 1) {
      __hip_atomic_store(bar, 0u, __ATOMIC_RELAXED, __HIP_MEMORY_SCOPE_AGENT);
      asm volatile("s_waitcnt vmcnt(0)" ::: "memory"); // reset lands before gen flips
      __hip_atomic_store(bar + 1, g + 1u, __ATOMIC_RELAXED, __HIP_MEMORY_SCOPE_AGENT);
    } else {
      while (__hip_atomic_load(bar + 1, __ATOMIC_RELAXED, __HIP_MEMORY_SCOPE_AGENT) == g)
        __builtin_amdgcn_s_sleep(2);
    }
    asm volatile("" ::: "memory");
  }
  __syncthreads();
}

// ---------------- prologue kernels ----------------
__global__ void __launch_bounds__(256) zero_k(float* wsf) {
  const unsigned i = blockIdx.x * 256u + threadIdx.x;
  if (i < 2u) ((unsigned*)wsf)[OFF_BAR + i] = 0u;
  if (i < 65536u) wsf[OFF_H0 + i] = 0.0f;   // h0R[2] + h1R[2] contiguous
}

__global__ void __launch_bounds__(256) cscore_k(const float* __restrict__ ctx,
                                                const float* __restrict__ Wa,
                                                const float* __restrict__ ba,
                                                float* __restrict__ wsf) {
  const int b = blockIdx.x;
  const int s = threadIdx.x >> 2, q = threadIdx.x & 3;
  const float* cp = ctx + ((size_t)b * S_ + s) * C_ + q * 128;
  const float* wp = Wa + H_ + q * 128;     // context half of Wa
  float acc = 0.f;
#pragma unroll 8
  for (int k = 0; k < 128; ++k) acc = fmaf(cp[k], wp[k], acc);
  acc += __shfl_xor(acc, 1);
  acc += __shfl_xor(acc, 2);
  if (q == 0) wsf[OFF_CS + b * S_ + s] = acc + ba[0];
}

__global__ void __launch_bounds__(256) cvt_wobf(const float* __restrict__ wo,
                                                unsigned short* __restrict__ dst) {
  const size_t i = ((size_t)blockIdx.x * 256u + threadIdx.x) * 4;
  float4 v = *(const float4*)(wo + i);
  ushort4 o;
  o.x = f2bf(v.x); o.y = f2bf(v.y); o.z = f2bf(v.z); o.w = f2bf(v.w);
  *(ushort4*)(dst + i) = o;
}

// ---------------- main persistent kernel ----------------
__global__ void __launch_bounds__(NTHR) mtad_main(Params p) {
  float* wsf = p.ws;
  int* wsi = (int*)p.ws;
  unsigned* barp = (unsigned*)p.ws;
  unsigned short* h1bf = (unsigned short*)(p.ws + OFF_H1BF);
  const unsigned short* wobf = (const unsigned short*)(p.ws + OFF_WOBF);
  const int bk = blockIdx.x;
  const int tx = threadIdx.x;

  // one shared blob, phase-dependent layout (phases separated by barriers)
  __shared__ __align__(16) char SMEM[49664];
  __shared__ float wlds[S_];
  __shared__ float hout[64];        // C: h1 stash for bf16 packing [16 u][4 b]
  __shared__ int   sxs;
  __shared__ float shs, sM;

  for (int t = 0; t < T_; ++t) {
    const int par = t & 1;
    // ================= Phase A: token resolve (refine) + attention ============
    if (bk < 128) {
      const int b = bk >> 2, quarter = bk & 3;
      float* rv   = (float*)SMEM;            // [512]
      int*   ri   = (int*)(SMEM + 2048);     // [512]
      float* rm   = (float*)(SMEM + 4096);   // [256]
      float* rs   = (float*)(SMEM + 5120);   // [256]
      float* sh1a = (float*)(SMEM + 6144);   // [512]
      float* attp = (float*)(SMEM + 8192);   // [4][128]
      const float* h1pR = wsf + OFF_H1 + par * (B_ * H_) + (size_t)b * H_;
      sh1a[tx] = ld_cf(h1pR + tx);
      int xtok;
      if (t > 0) {
        rv[tx] = ld_cf(wsf + OFF_A2V + b * 512 + tx);
        ri[tx] = ld_ci(wsi + OFF_A2I + b * 512 + tx);
        if (tx < 256) {
          rm[tx] = ld_cf(wsf + OFF_LSM + b * 256 + tx);
          rs[tx] = ld_cf(wsf + OFF_LSS + b * 256 + tx);
        }
        __syncthreads();
        if (tx < 64) {
          float M = rv[tx];
#pragma unroll
          for (int o = 64; o < 512; o += 64) M = fmaxf(M, rv[tx + o]);
          float m = rm[tx], s = rs[tx];
#pragma unroll
          for (int o = 64; o < 256; o += 64) lse_merge(m, s, rm[tx + o], rs[tx + o]);
#pragma unroll
          for (int d = 1; d < 64; d <<= 1) {
            M = fmaxf(M, __shfl_xor(M, d));
            float m2 = __shfl_xor(m, d), s2 = __shfl_xor(s, d);
            lse_merge(m, s, m2, s2);
          }
          if (tx == 0) {
            sM = M;
            if (quarter == 0) st_cf(wsf + OFF_LSEA + (t - 1) * B_ + b, m + logf(s));
          }
        }
        __syncthreads();
        // refine: exact fp32 logit for candidates near the bf16 max
        float best = -3.0e38f; int bestIdx = 0x7fffffff;
        {
          const float val = rv[tx]; const int idx = ri[tx];
          if (val >= sM - DELTA && idx < V_) {
            const float* wr = p.Wo + (size_t)idx * H_;
            float a0 = 0.f, a1 = 0.f, a2 = 0.f, a3 = 0.f;
            for (int k = 0; k < H_; k += 4) {
              a0 = fmaf(sh1a[k], wr[k], a0);
              a1 = fmaf(sh1a[k + 1], wr[k + 1], a1);
              a2 = fmaf(sh1a[k + 2], wr[k + 2], a2);
              a3 = fmaf(sh1a[k + 3], wr[k + 3], a3);
            }
            best = ((a0 + a1) + (a2 + a3)) + p.bo[idx];
            bestIdx = idx;
          }
        }
        __syncthreads();
        rv[tx] = best; ri[tx] = bestIdx;
        __syncthreads();
        if (tx < 64) {
          float av = rv[tx]; int ai = ri[tx];
#pragma unroll
          for (int o = 64; o < 512; o += 64) {
            const float av2 = rv[tx + o]; const int ai2 = ri[tx + o];
            if (av2 > av || (av2 == av && ai2 < ai)) { av = av2; ai = ai2; }
          }
#pragma unroll
          for (int d = 1; d < 64; d <<= 1) {
            const float av2 = __shfl_xor(av, d); const int ai2 = __shfl_xor(ai, d);
            if (av2 > av || (av2 == av && ai2 < ai)) { av = av2; ai = ai2; }
          }
          if (tx == 0) sxs = ai;
        }
        __syncthreads();
        xtok = sxs;
      } else {
        xtok = START_TOK;
      }
      // embedding -> inpR[b][0:256)
      if (quarter == 0 && tx < 256)
        st_cf(wsf + OFF_INP + (size_t)b * 768 + tx, p.embed[(size_t)xtok * E_ + tx]);
      // hscore = h1_prev[b] . Wa[0:512]
      rv[tx] = sh1a[tx] * p.Wa[tx];
      __syncthreads();
      if (tx < 64) {
        float v = 0.f;
#pragma unroll
        for (int o = 0; o < NTHR; o += 64) v += rv[tx + o];
#pragma unroll
        for (int d = 1; d < 64; d <<= 1) v += __shfl_xor(v, d);
        if (tx == 0) shs = v;
      }
      __syncthreads();
      if (tx < S_) {
        const float sc = tanhf(shs + wsf[OFF_CS + b * S_ + tx]);
        const float e = expf(sc);
        float sum = e;
#pragma unroll
        for (int d = 1; d < 64; d <<= 1) sum += __shfl_xor(sum, d);
        const float w = e / sum;
        wlds[tx] = w;
        if (quarter == 0)
          p.out[(size_t)B_ * T_ * V_ + ((size_t)b * T_ + t) * S_ + tx] = w;
      }
      __syncthreads();
      {
        const int cq = tx & 127, sq = tx >> 7;
        const float* cb = p.ctx + ((size_t)b * S_ + sq * 16) * C_ + quarter * 128 + cq;
        float a0 = 0.f;
#pragma unroll
        for (int s2 = 0; s2 < 16; ++s2)
          a0 = fmaf(wlds[sq * 16 + s2], cb[(size_t)s2 * C_], a0);
        attp[sq * 128 + cq] = a0;
      }
      __syncthreads();
      if (tx < 128)
        st_cf(wsf + OFF_INP + (size_t)b * 768 + 256 + quarter * 128 + tx,
              attp[tx] + attp[128 + tx] + attp[256 + tx] + attp[384 + tx]);
    }
    gbar(barp);
    // ================= Phase B: GRU layer 0 (block = 16 units x 4 batches) ====
    {
      const int ug = bk & 31, bg = bk >> 5;   // XCD-aware: same-XCD blocks share ug set
      const int b4 = bg * 4;
      float* sacts = (float*)SMEM;            // inp4[4][768] | h04[4][512]
      const float* inpR = wsf + OFF_INP;
      const float* h0prevR = wsf + OFF_H0 + par * (B_ * H_);
      {
        const unsigned long long* sp[5];
#pragma unroll
        for (int s2 = 0; s2 < 5; ++s2) {
          const int i = tx + s2 * NTHR;
          if (i < 1536)
            sp[s2] = (const unsigned long long*)(inpR + (size_t)(b4 + i / 384) * 768) + (i % 384);
          else {
            const int ii = i - 1536;
            sp[s2] = (const unsigned long long*)(h0prevR + (size_t)(b4 + ii / 256) * 512) + (ii % 256);
          }
        }
        unsigned long long vv[5];
#pragma unroll
        for (int s2 = 0; s2 < 5; ++s2)
          asm volatile("global_load_dwordx2 %0, %1, off sc0 sc1" : "=v"(vv[s2]) : "v"(sp[s2]));
        asm volatile("s_waitcnt vmcnt(0)" ::: "memory");
#pragma unroll
        for (int s2 = 0; s2 < 5; ++s2)
          ((unsigned long long*)sacts)[tx + s2 * NTHR] = vv[s2];
      }
      __syncthreads();
      const int u = tx >> 5, l = tx & 31;
      const int j = ug * 16 + u;
      float red[16];
#pragma unroll
      for (int q = 0; q < 16; ++q) red[q] = 0.f;
#pragma unroll
      for (int g = 0; g < 3; ++g) {
        const float* wx = p.Wih0 + (size_t)(g * H_ + j) * 768 + l * 24;
        float* dx = (g < 2) ? &red[g * 4] : &red[8];
#pragma unroll
        for (int c = 0; c < 6; ++c) {
          const float4 w = *(const float4*)(wx + c * 4);
#pragma unroll
          for (int b = 0; b < 4; ++b) {
            const float* a = &sacts[b * 768 + l * 24 + c * 4];
            dx[b] = fmaf(w.x, a[0], dx[b]); dx[b] = fmaf(w.y, a[1], dx[b]);
            dx[b] = fmaf(w.z, a[2], dx[b]); dx[b] = fmaf(w.w, a[3], dx[b]);
          }
        }
        const float* wh = p.Whh0 + (size_t)(g * H_ + j) * H_ + l * 16;
        float* dh = (g < 2) ? &red[g * 4] : &red[12];
#pragma unroll
        for (int c = 0; c < 4; ++c) {
          const float4 w = *(const float4*)(wh + c * 4);
#pragma unroll
          for (int b = 0; b < 4; ++b) {
            const float* a = &sacts[3072 + b * 512 + l * 16 + c * 4];
            dh[b] = fmaf(w.x, a[0], dh[b]); dh[b] = fmaf(w.y, a[1], dh[b]);
            dh[b] = fmaf(w.z, a[2], dh[b]); dh[b] = fmaf(w.w, a[3], dh[b]);
          }
        }
      }
#pragma unroll
      for (int d = 1; d < 32; d <<= 1)
#pragma unroll
        for (int q = 0; q < 16; ++q) red[q] += __shfl_xor(red[q], d);
      if (l < 4) {
        const float rr = sigf(red[l] + p.bih0[j] + p.bhh0[j]);
        const float zz = sigf(red[4 + l] + p.bih0[H_ + j] + p.bhh0[H_ + j]);
        const float nn = tanhf(red[8 + l] + p.bih0[2 * H_ + j] +
                               rr * (red[12 + l] + p.bhh0[2 * H_ + j]));
        const float hp = sacts[3072 + l * 512 + j];
        st_cf(wsf + OFF_H0 + (1 - par) * (B_ * H_) + (size_t)(b4 + l) * H_ + j,
              (1.f - zz) * nn + zz * hp);
      }
    }
    gbar(barp);
    // ================= Phase C: GRU layer 1 =================
    {
      const int ug = bk & 31, bg = bk >> 5;
      const int b4 = bg * 4;
      float* sacts = (float*)SMEM;            // x4[4][512] | h4[4][512]
      const float* h0newR = wsf + OFF_H0 + (1 - par) * (B_ * H_);
      const float* h1prevR = wsf + OFF_H1 + par * (B_ * H_);
      {
        const unsigned long long* sp[4];
#pragma unroll
        for (int s2 = 0; s2 < 4; ++s2) {
          const int i = tx + s2 * NTHR;
          if (i < 1024)
            sp[s2] = (const unsigned long long*)(h0newR + (size_t)(b4 + i / 256) * 512) + (i % 256);
          else {
            const int ii = i - 1024;
            sp[s2] = (const unsigned long long*)(h1prevR + (size_t)(b4 + ii / 256) * 512) + (ii % 256);
          }
        }
        unsigned long long vv[4];
#pragma unroll
        for (int s2 = 0; s2 < 4; ++s2)
          asm volatile("global_load_dwordx2 %0, %1, off sc0 sc1" : "=v"(vv[s2]) : "v"(sp[s2]));
        asm volatile("s_waitcnt vmcnt(0)" ::: "memory");
#pragma unroll
        for (int s2 = 0; s2 < 4; ++s2)
          ((unsigned long long*)sacts)[tx + s2 * NTHR] = vv[s2];
      }
      __syncthreads();
      const int u = tx >> 5, l = tx & 31;
      const int j = ug * 16 + u;
      float red[16];
#pragma unroll
      for (int q = 0; q < 16; ++q) red[q] = 0.f;
#pragma unroll
      for (int g = 0; g < 3; ++g) {
        const float* wx = p.Wih1 + (size_t)(g * H_ + j) * H_ + l * 16;
        float* dx = (g < 2) ? &red[g * 4] : &red[8];
#pragma unroll
        for (int c = 0; c < 4; ++c) {
          const float4 w = *(const float4*)(wx + c * 4);
#pragma unroll
          for (int b = 0; b < 4; ++b) {
            const float* a = &sacts[b * 512 + l * 16 + c * 4];
            dx[b] = fmaf(w.x, a[0], dx[b]); dx[b] = fmaf(w.y, a[1], dx[b]);
            dx[b] = fmaf(w.z, a[2], dx[b]); dx[b] = fmaf(w.w, a[3], dx[b]);
          }
        }
        const float* wh = p.Whh1 + (size_t)(g * H_ + j) * H_ + l * 16;
        float* dh = (g < 2) ? &red[g * 4] : &red[12];
#pragma unroll
        for (int c = 0; c < 4; ++c) {
          const float4 w = *(const float4*)(wh + c * 4);
#pragma unroll
          for (int b = 0; b < 4; ++b) {
            const float* a = &sacts[2048 + b * 512 + l * 16 + c * 4];
            dh[b] = fmaf(w.x, a[0], dh[b]); dh[b] = fmaf(w.y, a[1], dh[b]);
            dh[b] = fmaf(w.z, a[2], dh[b]); dh[b] = fmaf(w.w, a[3], dh[b]);
          }
        }
      }
#pragma unroll
      for (int d = 1; d < 32; d <<= 1)
#pragma unroll
        for (int q = 0; q < 16; ++q) red[q] += __shfl_xor(red[q], d);
      if (l < 4) {
        const float rr = sigf(red[l] + p.bih1[j] + p.bhh1[j]);
        const float zz = sigf(red[4 + l] + p.bih1[H_ + j] + p.bhh1[H_ + j]);
        const float nn = tanhf(red[8 + l] + p.bih1[2 * H_ + j] +
                               rr * (red[12 + l] + p.bhh1[2 * H_ + j]));
        const float hp = sacts[2048 + l * 512 + j];
        const float hnew = (1.f - zz) * nn + zz * hp;
        st_cf(wsf + OFF_H1 + (1 - par) * (B_ * H_) + (size_t)(b4 + l) * H_ + j, hnew);
        hout[u * 4 + l] = hnew;
      }
      __syncthreads();
      if (tx < 32) {   // pack 2 units -> one dword of bf16x2, coherent store
        const int b = tx & 3, pp = tx >> 2;
        const float h0v = hout[(pp * 2) * 4 + b];
        const float h1v = hout[(pp * 2 + 1) * 4 + b];
        const unsigned pk = (unsigned)f2bf(h0v) | ((unsigned)f2bf(h1v) << 16);
        st_ci((int*)(h1bf + ((size_t)t * B_ + b4 + b) * H_ + ug * 16 + pp * 2), (int)pk);
      }
    }
    gbar(barp);
    // ========== Phase D: bf16 MFMA logits scan (top2 + lse partials) =========
    {
      if (bk < NVB) {
        const int v0 = bk * VT;
        unsigned short* sh1b = (unsigned short*)SMEM;   // [32][520] padded
        float* slog = (float*)(SMEM + 33280);           // [32][128]
        {
          const unsigned long long* src =
              (const unsigned long long*)(h1bf + (size_t)t * B_ * H_);
          const unsigned long long* sp[8];
#pragma unroll
          for (int s2 = 0; s2 < 8; ++s2) {
            const int i = tx + s2 * NTHR;
            sp[s2] = src + (i >> 7) * 64 + (i & 127);
          }
          unsigned long long vv[8];
#pragma unroll
          for (int s2 = 0; s2 < 8; ++s2)
            asm volatile("global_load_dwordx2 %0, %1, off sc0 sc1" : "=v"(vv[s2]) : "v"(sp[s2]));
          asm volatile("s_waitcnt vmcnt(0)" ::: "memory");
#pragma unroll
          for (int s2 = 0; s2 < 8; ++s2) {
            const int i = tx + s2 * NTHR;
            ((unsigned long long*)sh1b)[(i >> 7) * 130 + (i & 127)] = vv[s2];
          }
        }
        __syncthreads();
        const int wv = tx >> 6, l = tx & 63;
        const int wn = wv >> 1, wm = wv & 1;
        const int lr = l & 15, lk = l >> 4;
        f32x4 acc0 = {0.f, 0.f, 0.f, 0.f}, acc1 = {0.f, 0.f, 0.f, 0.f};
        const unsigned short* wr0 = wobf + (size_t)(v0 + wn * 32 + lr) * H_ + lk * 8;
        const unsigned short* wr1 = wr0 + (size_t)16 * H_;
        const unsigned short* arow = sh1b + (wm * 16 + lr) * 520 + lk * 8;
#pragma unroll 4
        for (int kc = 0; kc < 16; ++kc) {
          bf16x8 a  = *(const bf16x8*)(arow + kc * 32);
          bf16x8 b0 = *(const bf16x8*)(wr0 + kc * 32);
          bf16x8 b1 = *(const bf16x8*)(wr1 + kc * 32);
          acc0 = __builtin_amdgcn_mfma_f32_16x16x32_bf16(a, b0, acc0, 0, 0, 0);
          acc1 = __builtin_amdgcn_mfma_f32_16x16x32_bf16(a, b1, acc1, 0, 0, 0);
        }
        const float bo0 = p.bo[v0 + wn * 32 + lr];
        const float bo1 = p.bo[v0 + wn * 32 + 16 + lr];
#pragma unroll
        for (int r = 0; r < 4; ++r) {
          const int b = wm * 16 + lk * 4 + r;
          slog[b * 128 + wn * 32 + lr] = acc0[r] + bo0;
          slog[b * 128 + wn * 32 + 16 + lr] = acc1[r] + bo1;
        }
        __syncthreads();
        {
          const int bb = tx >> 4, g = tx & 15;
          float v1 = -3.0e38f, v2 = -3.0e38f; int i1 = 0x7fffffff, i2 = 0x7fffffff;
          float m = -3.0e38f, s = 0.f;
#pragma unroll
          for (int jj = 0; jj < 8; ++jj) {
            const float val = slog[bb * 128 + g * 8 + jj];
            const int idx = v0 + g * 8 + jj;
            if (val > v1 || (val == v1 && idx < i1)) { v2 = v1; i2 = i1; v1 = val; i1 = idx; }
            else if (val > v2 || (val == v2 && idx < i2)) { v2 = val; i2 = idx; }
            if (val > m) { s = s * expf(m - val) + 1.f; m = val; } else s += expf(val - m);
          }
#pragma unroll
          for (int d = 1; d < 16; d <<= 1) {
            float w1 = __shfl_xor(v1, d); int j1 = __shfl_xor(i1, d);
            float w2 = __shfl_xor(v2, d); int j2 = __shfl_xor(i2, d);
            float m2 = __shfl_xor(m, d);  float s2 = __shfl_xor(s, d);
            if (w1 > v1 || (w1 == v1 && j1 < i1)) { v2 = v1; i2 = i1; v1 = w1; i1 = j1; }
            else if (w1 > v2 || (w1 == v2 && j1 < i2)) { v2 = w1; i2 = j1; }
            if (w2 > v2 || (w2 == v2 && j2 < i2)) {
              if (w2 > v1 || (w2 == v1 && j2 < i1)) { v2 = v1; i2 = i1; v1 = w2; i1 = j2; }
              else { v2 = w2; i2 = j2; }
            }
            lse_merge(m, s, m2, s2);
          }
          if (g == 0) {
            st_cf(wsf + OFF_A2V + bb * 512 + bk * 2, v1);
            st_cf(wsf + OFF_A2V + bb * 512 + bk * 2 + 1, v2);
            st_ci(wsi + OFF_A2I + bb * 512 + bk * 2, i1);
            st_ci(wsi + OFF_A2I + bb * 512 + bk * 2 + 1, i2);
            st_cf(wsf + OFF_LSM + bb * 256 + bk, m);
            st_cf(wsf + OFF_LSS + bb * 256 + bk, s);
          }
        }
      } else {
        if (tx < B_) {   // ghost blocks: neutral partials
          st_cf(wsf + OFF_A2V + tx * 512 + bk * 2, -3.0e38f);
          st_cf(wsf + OFF_A2V + tx * 512 + bk * 2 + 1, -3.0e38f);
          st_ci(wsi + OFF_A2I + tx * 512 + bk * 2, 0x7fffffff);
          st_ci(wsi + OFF_A2I + tx * 512 + bk * 2 + 1, 0x7fffffff);
          st_cf(wsf + OFF_LSM + tx * 256 + bk, -3.0e38f);
          st_cf(wsf + OFF_LSS + tx * 256 + bk, 0.f);
        }
      }
    }
    if (t < T_ - 1) gbar(barp);
  }
}

// ---------------- epilogue: lse for last step ----------------
__global__ void __launch_bounds__(256) epi_lse(float* __restrict__ wsf) {
  const int b = blockIdx.x, tx = threadIdx.x;
  __shared__ float rm[256], rs[256];
  rm[tx] = wsf[OFF_LSM + b * 256 + tx];
  rs[tx] = wsf[OFF_LSS + b * 256 + tx];
  __syncthreads();
  if (tx < 64) {
    float m = rm[tx], s = rs[tx];
#pragma unroll
    for (int o = 64; o < 256; o += 64) lse_merge(m, s, rm[tx + o], rs[tx + o]);
#pragma unroll
    for (int d = 1; d < 64; d <<= 1) {
      float m2 = __shfl_xor(m, d), s2 = __shfl_xor(s, d);
      lse_merge(m, s, m2, s2);
    }
    if (tx == 0) wsf[OFF_LSEA + 31 * B_ + b] = m + logf(s);
  }
}

// ---------------- final batched logp GEMM (bf16 MFMA) ----------------
__global__ void __launch_bounds__(256) gemm_logp(const unsigned short* __restrict__ h1bf,
                                                 const unsigned short* __restrict__ wobf,
                                                 const float* __restrict__ bo,
                                                 const float* __restrict__ lsea,
                                                 float* __restrict__ out) {
  __shared__ __align__(16) unsigned short As[2][128 * 40];  // rows padded to 80B
  __shared__ __align__(16) unsigned short Bs[2][128 * 40];
  const int tx = threadIdx.x;
  const int v0 = blockIdx.x * 128, m0 = blockIdx.y * 128;
  const int w = tx >> 6, l = tx & 63;
  const int wm = w >> 1, wn = w & 1;
  f32x4 acc[4][4];
#pragma unroll
  for (int i = 0; i < 4; ++i)
#pragma unroll
    for (int j = 0; j < 4; ++j) acc[i][j] = (f32x4){0.f, 0.f, 0.f, 0.f};

#define GSTAGE(ci, kc) {                                                        \
    _Pragma("unroll")                                                           \
    for (int e = 0; e < 2; ++e) {                                               \
      const int seg = tx * 2 + e, row = seg >> 2, s = seg & 3;                  \
      *(uint4*)&As[ci][row * 40 + s * 8] =                                      \
          *(const uint4*)(h1bf + (size_t)(m0 + row) * H_ + (kc) * 32 + s * 8);  \
      *(uint4*)&Bs[ci][row * 40 + s * 8] =                                      \
          *(const uint4*)(wobf + (size_t)(v0 + row) * H_ + (kc) * 32 + s * 8);  \
    } }

  GSTAGE(0, 0);
  __syncthreads();
  for (int kc = 0; kc < 16; ++kc) {
    const int cur = kc & 1;
    if (kc < 15) GSTAGE(cur ^ 1, kc + 1);
    const int lk = (l >> 4) * 8, lr = l & 15;
    bf16x8 af[4], bf[4];
#pragma unroll
    for (int f = 0; f < 4; ++f) {
      af[f] = *(const bf16x8*)&As[cur][(wm * 64 + f * 16 + lr) * 40 + lk];
      bf[f] = *(const bf16x8*)&Bs[cur][(wn * 64 + f * 16 + lr) * 40 + lk];
    }
#pragma unroll
    for (int fm = 0; fm < 4; ++fm)
#pragma unroll
      for (int fn = 0; fn < 4; ++fn)
        acc[fm][fn] = __builtin_amdgcn_mfma_f32_16x16x32_bf16(af[fm], bf[fn], acc[fm][fn], 0, 0, 0);
    __syncthreads();
  }
#undef GSTAGE
  const int lr = l & 15, lq = l >> 4;
#pragma unroll
  for (int fm = 0; fm < 4; ++fm) {
#pragma unroll
    for (int fn = 0; fn < 4; ++fn) {
      const int v = v0 + wn * 64 + fn * 16 + lr;
      const float bov = bo[v];
#pragma unroll
      for (int r = 0; r < 4; ++r) {
        const int M = m0 + wm * 64 + fm * 16 + lq * 4 + r;
        const int tt = M >> 5, b = M & 31;
        out[((size_t)b * T_ + tt) * (size_t)V_ + v] = acc[fm][fn][r] + bov - lsea[tt * B_ + b];
      }
    }
  }
}

// ---------------- host launch ----------------
extern "C" void kernel_launch(void* const* d_in, const int* in_sizes, int n_in,
                              void* d_out, int out_size, void* d_ws, size_t ws_size,
                              hipStream_t stream) {
  (void)in_sizes; (void)n_in; (void)out_size;
  if (ws_size < (size_t)WS_FLOATS * sizeof(float)) return;  // workspace too small

  const float* ctx   = (const float*)d_in[0];
  // d_in[1] = max_len (scalar, == 32, hardcoded)
  const float* embed = (const float*)d_in[2];
  const float* Wa    = (const float*)d_in[3];
  const float* ba    = (const float*)d_in[4];
  const float* Wih0  = (const float*)d_in[5];
  const float* Whh0  = (const float*)d_in[6];
  const float* bih0  = (const float*)d_in[7];
  const float* bhh0  = (const float*)d_in[8];
  const float* Wih1  = (const float*)d_in[9];
  const float* Whh1  = (const float*)d_in[10];
  const float* bih1  = (const float*)d_in[11];
  const float* bhh1  = (const float*)d_in[12];
  const float* Wo    = (const float*)d_in[13];
  const float* bo    = (const float*)d_in[14];
  float* ws  = (float*)d_ws;
  float* out = (float*)d_out;

  zero_k<<<dim3(256), dim3(256), 0, stream>>>(ws);
  cscore_k<<<dim3(32), dim3(256), 0, stream>>>(ctx, Wa, ba, ws);
  cvt_wobf<<<dim3(16000), dim3(256), 0, stream>>>(Wo, (unsigned short*)(ws + OFF_WOBF));

  Params p;
  p.ctx = ctx; p.embed = embed; p.Wa = Wa;
  p.Wih0 = Wih0; p.Whh0 = Whh0; p.bih0 = bih0; p.bhh0 = bhh0;
  p.Wih1 = Wih1; p.Whh1 = Whh1; p.bih1 = bih1; p.bhh1 = bhh1;
  p.Wo = Wo; p.bo = bo; p.ws = ws; p.out = out;
  mtad_main<<<dim3(NBLK), dim3(NTHR), 0, stream>>>(p);

  epi_lse<<<dim3(32), dim3(256), 0, stream>>>(ws);
  gemm_logp<<<dim3(250, 8), dim3(256), 0, stream>>>(
      (const unsigned short*)(ws + OFF_H1BF), (const unsigned short*)(ws + OFF_WOBF),
      bo, ws + OFF_LSEA, out);
}